// Round 3
// baseline (107.814 us; speedup 1.0000x reference)
//
#include <hip/hip_runtime.h>
#include <hip/hip_bf16.h>

// SimCLR loss, N=8192, D=128, T=0.1.
//  k1 (prep):  row L2-normalize fp32 -> bf16 znb (unscaled) + znbs (x 10*log2e);
//              selfe[i] = exp2(sum bf16(s*a)*bf16(a)) matching the MFMA diagonal;
//              poslog[i] = 10 * normalized fp32 dot(z_i, z_{i^4096}) (= log pos).
//  k2 (sim):   rowsum of exp2(mfma(znbs_i, znb_j)) over ALL j, no masking;
//              partials[16][N], no atomics.
//  k3a/k3b:    denom = sum(partials) - selfe; loss = mean(log(denom) - poslog).
//
// Loss identity: -log(pos/(pos+neg)) = log(rowsum - self) - log(pos); the single
// positive per row sits at j = i ^ 4096 (indexes = tile(arange(N/2), 2)).

constexpr int N = 8192;
constexpr int D = 128;
constexpr float SCALE = 14.4269504088896341f;  // 10 * log2(e)

typedef short bf16x8 __attribute__((ext_vector_type(8)));
typedef float f32x4 __attribute__((ext_vector_type(4)));

#if __has_builtin(__builtin_amdgcn_exp2f)
#define EXP2(x) __builtin_amdgcn_exp2f(x)
#else
#define EXP2(x) exp2f(x)
#endif

static __device__ __forceinline__ unsigned short f2bf(float x) {
  __hip_bfloat16 h = __float2bfloat16(x);  // RTNE
  unsigned short u;
  __builtin_memcpy(&u, &h, 2);
  return u;
}
static __device__ __forceinline__ float bf2f(unsigned short u) {
  unsigned int x = ((unsigned int)u) << 16;
  float f;
  __builtin_memcpy(&f, &x, 4);
  return f;
}

// ------------- kernel 1: normalize + bf16 convert + self-term + pos-term -------------
__global__ __launch_bounds__(256) void simclr_prep(const float* __restrict__ z,
                                                   unsigned short* __restrict__ znb,
                                                   unsigned short* __restrict__ znbs,
                                                   float* __restrict__ selfe,
                                                   float* __restrict__ poslog) {
  const int row = blockIdx.x * 4 + (threadIdx.x >> 6);
  const int par = row ^ (N / 2);
  const int lane = threadIdx.x & 63;
  const float2 v = *(const float2*)(z + row * D + lane * 2);
  const float2 b = *(const float2*)(z + par * D + lane * 2);
  float ss = v.x * v.x + v.y * v.y;
  float sb = b.x * b.x + b.y * b.y;
  float dp = v.x * b.x + v.y * b.y;
#pragma unroll
  for (int m = 1; m < 64; m <<= 1) {
    ss += __shfl_xor(ss, m);
    sb += __shfl_xor(sb, m);
    dp += __shfl_xor(dp, m);
  }
  const float rn = rsqrtf(ss);
  const float a0 = v.x * rn, a1 = v.y * rn;
  const unsigned short u0 = f2bf(a0), u1 = f2bf(a1);
  const unsigned short s0 = f2bf(a0 * SCALE), s1 = f2bf(a1 * SCALE);
  *(unsigned int*)(znb + row * D + lane * 2) = (unsigned int)u0 | ((unsigned int)u1 << 16);
  *(unsigned int*)(znbs + row * D + lane * 2) = (unsigned int)s0 | ((unsigned int)s1 << 16);
  // self dot with exactly the MFMA's bf16 products (fp32 sum; order-only mismatch ~1e-5)
  float sa = bf2f(s0) * bf2f(u0) + bf2f(s1) * bf2f(u1);
#pragma unroll
  for (int m = 1; m < 64; m <<= 1) sa += __shfl_xor(sa, m);
  if (lane == 0) {
    selfe[row] = EXP2(sa);
    poslog[row] = 10.0f * dp * rsqrtf(ss * sb);
  }
}

// ---------------- kernel 2: similarity row-sums (mask-free) ----------------
// grid = (N/128) * 16 = 1024 blocks; block = 256 threads (4 waves).
// Each block: 128 rows x 512 cols. Wave w owns rows [w*32, w*32+32).
__global__ __launch_bounds__(256) void simclr_sim(const unsigned short* __restrict__ znb,
                                                  const unsigned short* __restrict__ znbs,
                                                  float* __restrict__ partials) {
  __shared__ unsigned short lb[128 * 128];  // 32KB B-subtile, XOR-swizzled rows
  char* lbc = (char*)lb;

  const int bi = blockIdx.x;
  const int RB = (bi >> 4) << 7;   // row-block base (x128)
  const int CB = (bi & 15) << 9;   // col-chunk base (x512)
  const int tid = threadIdx.x;
  const int lane = tid & 63;
  const int w = tid >> 6;
  const int l15 = lane & 15, l4 = lane >> 4;

  // A fragments (pre-scaled by 10*log2e) in registers for the whole sweep.
  // A layout (16x16x32): lane holds A[l&15][(l>>4)*8 + 0..7]
  bf16x8 afrag[2][4];
  {
    const unsigned short* ab = znbs + (RB + w * 32 + l15) * D + l4 * 8;
#pragma unroll
    for (int t = 0; t < 2; ++t)
#pragma unroll
      for (int s = 0; s < 4; ++s)
        afrag[t][s] = *(const bf16x8*)(ab + t * 16 * D + s * 32);
  }

  float dpart[8];
#pragma unroll
  for (int k = 0; k < 8; ++k) dpart[k] = 0.f;

  // T14-style async stage: preload chunk 0 into regs
  uint4 st[8];
  int gcol[8], grow[8], db[8];
#pragma unroll
  for (int it = 0; it < 8; ++it) {
    const int c = it * 256 + tid;
    const int rr = c >> 4, sl = c & 15;
    grow[it] = rr;
    gcol[it] = sl * 8;
    db[it] = rr * 256 + ((sl * 16) ^ ((rr & 7) << 4));
    st[it] = *(const uint4*)(znb + (CB + rr) * D + gcol[it]);
  }

  for (int jc = 0; jc < 4; ++jc) {
    __syncthreads();  // previous-iter LDS reads done before overwrite
#pragma unroll
    for (int it = 0; it < 8; ++it) *(uint4*)(lbc + db[it]) = st[it];
    __syncthreads();
    if (jc < 3) {
      const int CJ = CB + (jc + 1) * 128;
#pragma unroll
      for (int it = 0; it < 8; ++it)
        st[it] = *(const uint4*)(znb + (CJ + grow[it]) * D + gcol[it]);
    }

#pragma unroll
    for (int jt = 0; jt < 8; ++jt) {
      // B layout: lane holds B[(l>>4)*8 + 0..7][l&15] = zn[jcol][k]
      bf16x8 bfrag[4];
      const int jr = jt * 16 + l15;
      const int swz = (jr & 7) << 4;
#pragma unroll
      for (int s = 0; s < 4; ++s) {
        const int byte = jr * 256 + ((s * 64 + l4 * 16) ^ swz);
        bfrag[s] = *(const bf16x8*)(lbc + byte);
      }
      f32x4 acc0 = {0.f, 0.f, 0.f, 0.f}, acc1 = {0.f, 0.f, 0.f, 0.f};
#pragma unroll
      for (int s = 0; s < 4; ++s) {
        acc0 = __builtin_amdgcn_mfma_f32_16x16x32_bf16(afrag[0][s], bfrag[s], acc0, 0, 0, 0);
        acc1 = __builtin_amdgcn_mfma_f32_16x16x32_bf16(afrag[1][s], bfrag[s], acc1, 0, 0, 0);
      }
      // acc already = 10*log2(e)*dot (A pre-scaled): just exp2 + accumulate
#pragma unroll
      for (int r = 0; r < 4; ++r) dpart[r] += EXP2(acc0[r]);
#pragma unroll
      for (int r = 0; r < 4; ++r) dpart[4 + r] += EXP2(acc1[r]);
    }
  }

  // reduce across the 16 column-lanes; lanes {0,16,32,48} hold full row sums
#pragma unroll
  for (int m = 1; m < 16; m <<= 1)
#pragma unroll
    for (int k = 0; k < 8; ++k) dpart[k] += __shfl_xor(dpart[k], m);

  if (l15 == 0) {
    // C/D layout: row = (lane>>4)*4 + r (+16 per t), col = lane&15
    float* pp = partials + (bi & 15) * N + RB + w * 32 + l4 * 4;
#pragma unroll
    for (int t = 0; t < 2; ++t)
#pragma unroll
      for (int r = 0; r < 4; ++r)
        pp[t * 16 + r] = dpart[t * 4 + r];
  }
}

// ---------------- kernel 3a: per-row loss, per-block partial sums ----------------
__global__ __launch_bounds__(256) void simclr_rowloss(const float* __restrict__ partials,
                                                      const float* __restrict__ selfe,
                                                      const float* __restrict__ poslog,
                                                      float* __restrict__ bsum) {
  const int tid = threadIdx.x;
  const int i = blockIdx.x * 256 + tid;
  float d = -selfe[i];
#pragma unroll
  for (int cb = 0; cb < 16; ++cb) d += partials[cb * N + i];
  float s = logf(d) - poslog[i];
#pragma unroll
  for (int m = 1; m < 64; m <<= 1) s += __shfl_xor(s, m);
  __shared__ float acc[4];
  if ((tid & 63) == 0) acc[tid >> 6] = s;
  __syncthreads();
  if (tid == 0) bsum[blockIdx.x] = acc[0] + acc[1] + acc[2] + acc[3];
}

// ---------------- kernel 3b: final scalar ----------------
__global__ __launch_bounds__(64) void simclr_final(const float* __restrict__ bsum,
                                                   float* __restrict__ out) {
  const int tid = threadIdx.x;
  float s = (tid < 32) ? bsum[tid] : 0.f;
#pragma unroll
  for (int m = 1; m < 64; m <<= 1) s += __shfl_xor(s, m);
  if (tid == 0) out[0] = s * (1.0f / N);
}

extern "C" void kernel_launch(void* const* d_in, const int* in_sizes, int n_in,
                              void* d_out, int out_size, void* d_ws, size_t ws_size,
                              hipStream_t stream) {
  const float* z = (const float*)d_in[0];
  float* out = (float*)d_out;

  float* partials = (float*)d_ws;                      // 16*N
  float* selfe = partials + 16 * N;                    // N
  float* poslog = selfe + N;                           // N
  float* bsum = poslog + N;                            // 32 (pad to 64)
  unsigned short* znb = (unsigned short*)(bsum + 64);  // N*D bf16 (16B-aligned)
  unsigned short* znbs = znb + N * D;                  // N*D bf16

  simclr_prep<<<N / 4, 256, 0, stream>>>(z, znb, znbs, selfe, poslog);
  simclr_sim<<<(N / 128) * 16, 256, 0, stream>>>(znb, znbs, partials);
  simclr_rowloss<<<N / 256, 256, 0, stream>>>(partials, selfe, poslog, bsum);
  simclr_final<<<1, 64, 0, stream>>>(bsum, out);
}